// Round 8
// baseline (624.802 us; speedup 1.0000x reference)
//
#include <hip/hip_runtime.h>
#include <math.h>
#include <float.h>

#define NN 65536
#define EE 1048576
#define DD 512
#define BB 64
#define SPLIT 8

// native (non-CAS) device-scope float atomic add
__device__ __forceinline__ void fadd(float* p, float v) {
    unsafeAtomicAdd(p, v);
}

__device__ __forceinline__ int lowerb(const int* __restrict__ a, int n, int v) {
    int lo = 0, hi = n;
    while (lo < hi) { int mid = (lo + hi) >> 1; if (a[mid] < v) lo = mid + 1; else hi = mid; }
    return lo;
}

__device__ __forceinline__ float dot4(float4 a, float4 b) {
    return fmaf(a.x, b.x, fmaf(a.y, b.y, fmaf(a.z, b.z, a.w * b.w)));
}

// ---- DPP wave reduce: sum lands in lane 63, pure VALU (no DS pipe) ----
template<int CTRL>
__device__ __forceinline__ float dppadd(float v) {
    union { float f; int i; } u, r;
    u.f = v;
    r.i = __builtin_amdgcn_update_dpp(0, u.i, CTRL, 0xF, 0xF, true);
    return v + r.f;
}
__device__ __forceinline__ float wave_sum63(float v) {
    v = dppadd<0x111>(v);   // row_shr:1
    v = dppadd<0x112>(v);   // row_shr:2
    v = dppadd<0x114>(v);   // row_shr:4
    v = dppadd<0x118>(v);   // row_shr:8  -> lane15 of each row16 holds row sum
    v = dppadd<0x142>(v);   // row_bcast:15
    v = dppadd<0x143>(v);   // row_bcast:31 -> lane63 holds wave sum
    return v;
}

// ---- Kernel P: precompute g*W columns + reduction scalars (input-only) ----
// gw : [2][3][DD]   g[d]*W[d][c]
// cAB: [2][8]       c0..2 = sum(g*Wc), c3..5 = sum(b*Wc)+bk[c]
__global__ __launch_bounds__(512) void prep_kernel(
    const float* __restrict__ g_i, const float* __restrict__ b_i,
    const float* __restrict__ g_n, const float* __restrict__ b_n,
    const float* __restrict__ W_i, const float* __restrict__ bk_i,
    const float* __restrict__ W_n, const float* __restrict__ bk_n,
    float* __restrict__ gw, float* __restrict__ cAB)
{
    int t = blockIdx.x;
    const float* g  = t ? g_n : g_i;
    const float* b  = t ? b_n : b_i;
    const float* W  = t ? W_n : W_i;
    const float* bk = t ? bk_n : bk_i;
    int d = threadIdx.x;
    float gv = g[d], bv = b[d];
    float w0 = W[d * 3 + 0], w1 = W[d * 3 + 1], w2 = W[d * 3 + 2];
    float v0 = gv * w0, v1 = gv * w1, v2 = gv * w2;
    gw[((size_t)t * 3 + 0) * DD + d] = v0;
    gw[((size_t)t * 3 + 1) * DD + d] = v1;
    gw[((size_t)t * 3 + 2) * DD + d] = v2;
    __shared__ float red[8];
    float vals[6] = { v0, v1, v2, bv * w0, bv * w1, bv * w2 };
    #pragma unroll
    for (int c = 0; c < 6; ++c) {
        float v = vals[c];
        #pragma unroll
        for (int o = 32; o; o >>= 1) v += __shfl_xor(v, o);
        if ((d & 63) == 0) red[d >> 6] = v;
        __syncthreads();
        if (d == 0) {
            float sum = 0.0f;
            #pragma unroll
            for (int w = 0; w < 8; ++w) sum += red[w];
            cAB[t * 8 + c] = sum + (c >= 3 ? bk[c - 3] : 0.0f);
        }
        __syncthreads();
    }
}

// ---- Kernel A: fused LayerNorm stats + kqv projection (round-4 best variant) ----
__global__ __launch_bounds__(256) void ln_kqv_kernel(
    const float* __restrict__ x_i, const float* __restrict__ x_n,
    const float* __restrict__ gw, const float* __restrict__ cAB,
    const float* __restrict__ krw, const float* __restrict__ krb,
    const float* __restrict__ vrw, const float* __restrict__ vrb,
    const float* __restrict__ prel,
    float2* __restrict__ mr_o, float2* __restrict__ ktvt2, float* __restrict__ qp)
{
    // grid = 2*NN/8 = 16384 blocks; 8192 per type; 2 rows per wave
    const int t  = blockIdx.x >> 13;
    const int nb = blockIdx.x & 8191;
    const float* x = t ? x_n : x_i;
    const int lane = threadIdx.x & 63;
    const int w    = threadIdx.x >> 6;
    const int row0 = nb * 8 + w * 2;

    const float4* xr0 = (const float4*)(x + (size_t)row0 * DD);
    const float4* xr1 = (const float4*)(x + (size_t)(row0 + 1) * DD);
    float4 xa0 = xr0[lane], xb0 = xr0[lane + 64];
    float4 xa1 = xr1[lane], xb1 = xr1[lane + 64];

    const float4* g0 = (const float4*)(gw + ((size_t)t * 3 + 0) * DD);
    const float4* g1 = (const float4*)(gw + ((size_t)t * 3 + 1) * DD);
    const float4* g2 = (const float4*)(gw + ((size_t)t * 3 + 2) * DD);
    float4 w0a = g0[lane], w0b = g0[lane + 64];
    float4 w1a = g1[lane], w1b = g1[lane + 64];
    float4 w2a = g2[lane], w2b = g2[lane + 64];

    const float* c = cAB + t * 8;
    float c0 = c[0], c1 = c[1], c2 = c[2], c3 = c[3], c4 = c[4], c5 = c[5];
    const int relk = t, relq = 1 - t;
    float ksc = krw[relk], kbi = krb[relk];
    float vsc = vrw[relk], vbi = vrb[relk];
    float psc = prel[relq];

    float s0  = xa0.x + xa0.y + xa0.z + xa0.w + xb0.x + xb0.y + xb0.z + xb0.w;
    float ss0 = dot4(xa0, xa0) + dot4(xb0, xb0);
    float p00 = dot4(xa0, w0a) + dot4(xb0, w0b);
    float p01 = dot4(xa0, w1a) + dot4(xb0, w1b);
    float p02 = dot4(xa0, w2a) + dot4(xb0, w2b);
    float s1  = xa1.x + xa1.y + xa1.z + xa1.w + xb1.x + xb1.y + xb1.z + xb1.w;
    float ss1 = dot4(xa1, xa1) + dot4(xb1, xb1);
    float p10 = dot4(xa1, w0a) + dot4(xb1, w0b);
    float p11 = dot4(xa1, w1a) + dot4(xb1, w1b);
    float p12 = dot4(xa1, w2a) + dot4(xb1, w2b);

    s0  = wave_sum63(s0);   s1  = wave_sum63(s1);
    ss0 = wave_sum63(ss0);  ss1 = wave_sum63(ss1);
    p00 = wave_sum63(p00);  p10 = wave_sum63(p10);
    p01 = wave_sum63(p01);  p11 = wave_sum63(p11);
    p02 = wave_sum63(p02);  p12 = wave_sum63(p12);

    if (lane == 63) {
        {
            float mean = s0 * (1.0f / DD);
            float var  = ss0 * (1.0f / DD) - mean * mean;
            float rstd = rsqrtf(var + 1e-5f);
            float kv = rstd * (p00 - mean * c0) + c3;
            float qv = rstd * (p01 - mean * c1) + c4;
            float vv = rstd * (p02 - mean * c2) + c5;
            int gn = t * NN + row0;
            mr_o[gn]  = make_float2(mean, rstd);
            ktvt2[gn] = make_float2(kv * ksc + kbi, vv * vsc + vbi);
            qp[gn]    = qv * psc;
        }
        {
            float mean = s1 * (1.0f / DD);
            float var  = ss1 * (1.0f / DD) - mean * mean;
            float rstd = rsqrtf(var + 1e-5f);
            float kv = rstd * (p10 - mean * c0) + c3;
            float qv = rstd * (p11 - mean * c1) + c4;
            float vv = rstd * (p12 - mean * c2) + c5;
            int gn = t * NN + row0 + 1;
            mr_o[gn]  = make_float2(mean, rstd);
            ktvt2[gn] = make_float2(kv * ksc + kbi, vv * vsc + vbi);
            qp[gn]    = qv * psc;
        }
    }
}

// ---- Kernel B: fused edge attention — direct device atomics into S ----
// Replaces edge_scatter + bucket_reduce (payload roundtrip, LDS atomics,
// cursor pass all eliminated). dst uniform over 64K nodes -> ~16 edges/node
// avg, negligible same-address contention; S (1MB) is L2-resident.
// blockIdx>>10: 0 = i2n edges (dst=net, region 1), 1 = n2i (dst=inst, region 0)
__global__ __launch_bounds__(256) void edge_attn_kernel(
    const int* __restrict__ ei_i2n, const int* __restrict__ ei_n2i,
    const float* __restrict__ ktvt, const float* __restrict__ qp,
    float* __restrict__ S)
{
    int es = blockIdx.x >> 10;          // 1024 blocks per direction
    int wg = blockIdx.x & 1023;
    const int* ei = es ? ei_n2i : ei_i2n;
    int soff = es ? NN : 0;             // src type base in ktvt
    int qoff = es ? 0 : NN;             // dst type base in qp
    int r    = es ? 0 : 1;              // dst region in S
    int e0 = (wg * 256 + threadIdx.x) * 4;
    int4 s4 = *(const int4*)(ei + e0);
    int4 d4 = *(const int4*)(ei + EE + e0);
    const float2* kt = (const float2*)ktvt + soff;
    const float*  q  = qp + qoff;
    float* Sb = S + (size_t)r * NN * 2;
    float2 kv0 = kt[s4.x], kv1 = kt[s4.y], kv2 = kt[s4.z], kv3 = kt[s4.w];
    float q0 = q[d4.x], q1 = q[d4.y], q2 = q[d4.z], q3 = q[d4.w];
    float e0_ = __expf(q0 * kv0.x);
    float e1_ = __expf(q1 * kv1.x);
    float e2_ = __expf(q2 * kv2.x);
    float e3_ = __expf(q3 * kv3.x);
    fadd(&Sb[2 * d4.x],     e0_);
    fadd(&Sb[2 * d4.x + 1], e0_ * kv0.y);
    fadd(&Sb[2 * d4.y],     e1_);
    fadd(&Sb[2 * d4.y + 1], e1_ * kv1.y);
    fadd(&Sb[2 * d4.z],     e2_);
    fadd(&Sb[2 * d4.z + 1], e2_ * kv2.y);
    fadd(&Sb[2 * d4.w],     e3_);
    fadd(&Sb[2 * d4.w + 1], e3_ * kv3.y);
}

// ---- Kernel C: node score (exact GELU) + per-batch exp-sum ----
__global__ __launch_bounds__(256) void score_bsum_kernel(
    const float2* __restrict__ S,
    const float* __restrict__ wout_i, const float* __restrict__ bout_i,
    const float* __restrict__ wout_n, const float* __restrict__ bout_n,
    const int* __restrict__ batch_i, const int* __restrict__ batch_n,
    float* __restrict__ esc, float* __restrict__ bsum)
{
    __shared__ float lsum[BB];
    int tid = threadIdx.x;
    if (tid < BB) lsum[tid] = 0.0f;
    __syncthreads();
    int idx = blockIdx.x * 256 + tid;
    int t = idx >> 16;          // N = 2^16
    int n = idx & (NN - 1);
    float2 sv = S[idx];
    float aggr = (sv.x > 0.0f) ? sv.y / sv.x : 0.0f;
    float w  = t ? wout_n[0] : wout_i[0];
    float b0 = t ? bout_n[0] : bout_i[0];
    float z  = fmaf(aggr, w, b0);
    float sc = 0.5f * z * (1.0f + erff(z * 0.70710678118654752440f));
    float e  = __expf(sc);
    esc[idx] = e;
    int bb = t ? batch_n[n] : batch_i[n];
    atomicAdd(&lsum[bb], e);          // LDS atomic: native
    __syncthreads();
    if (tid < BB && lsum[tid] != 0.0f) fadd(&bsum[t * BB + tid], lsum[tid]);
}

// ---- Kernel D: pooling — float4 loads, 4 row-phases per block, LDS fold ----
__global__ __launch_bounds__(512) void pool_kernel(
    const float* __restrict__ x_i, const float* __restrict__ x_n,
    const float* __restrict__ g_i, const float* __restrict__ gbi,
    const float* __restrict__ g_n, const float* __restrict__ gbn,
    const float2* __restrict__ mr_, const float* __restrict__ esc,
    const int* __restrict__ batch_i, const int* __restrict__ batch_n,
    const float* __restrict__ bsum,
    float* __restrict__ addp, float* __restrict__ mxp)
{
    int gi = blockIdx.x;
    int t    = gi >> 9;                 // BB*SPLIT = 512 blocks per type
    int bi   = gi & 511;
    int b    = bi >> 3;                 // SPLIT = 8
    int part = bi & (SPLIT - 1);
    const float* x     = t ? x_n : x_i;
    const float* gwp   = t ? g_n : g_i;
    const float* gbp   = t ? gbn : gbi;
    const int*   batch = t ? batch_n : batch_i;
    const float2* mr   = mr_ + (size_t)t * NN;
    const float* es    = esc + (size_t)t * NN;
    int start = lowerb(batch, NN, b);
    int end   = lowerb(batch, NN, b + 1);
    int len   = end - start;
    int chunk = (len + SPLIT - 1) / SPLIT;
    int i0 = start + part * chunk;
    int i1 = min(i0 + chunk, end);
    if (i0 > i1) i1 = i0;
    int tid = threadIdx.x;
    int ro  = tid >> 7;                 // row offset 0..3
    int c4  = (tid & 127) << 2;         // column base 0..508
    float4 gv = *(const float4*)(gwp + c4);
    float4 bv = *(const float4*)(gbp + c4);
    float inv = 1.0f / bsum[t * BB + b];
    float4 acc = make_float4(0.0f, 0.0f, 0.0f, 0.0f);
    float4 amx = make_float4(-FLT_MAX, -FLT_MAX, -FLT_MAX, -FLT_MAX);
    int i = i0;
    for (; i + 8 <= i1; i += 8) {
        int r0 = i + ro, r1 = i + 4 + ro;
        float4 xv0 = *(const float4*)(x + (size_t)r0 * DD + c4);
        float4 xv1 = *(const float4*)(x + (size_t)r1 * DD + c4);
        float w0 = es[r0] * inv; float2 q0 = mr[r0];
        float w1 = es[r1] * inv; float2 q1 = mr[r1];
        float4 v0, v1;
        v0.x = ((xv0.x - q0.x) * q0.y * gv.x + bv.x) * w0;
        v0.y = ((xv0.y - q0.x) * q0.y * gv.y + bv.y) * w0;
        v0.z = ((xv0.z - q0.x) * q0.y * gv.z + bv.z) * w0;
        v0.w = ((xv0.w - q0.x) * q0.y * gv.w + bv.w) * w0;
        v1.x = ((xv1.x - q1.x) * q1.y * gv.x + bv.x) * w1;
        v1.y = ((xv1.y - q1.x) * q1.y * gv.y + bv.y) * w1;
        v1.z = ((xv1.z - q1.x) * q1.y * gv.z + bv.z) * w1;
        v1.w = ((xv1.w - q1.x) * q1.y * gv.w + bv.w) * w1;
        acc.x += v0.x + v1.x; acc.y += v0.y + v1.y;
        acc.z += v0.z + v1.z; acc.w += v0.w + v1.w;
        amx.x = fmaxf(amx.x, fmaxf(v0.x, v1.x));
        amx.y = fmaxf(amx.y, fmaxf(v0.y, v1.y));
        amx.z = fmaxf(amx.z, fmaxf(v0.z, v1.z));
        amx.w = fmaxf(amx.w, fmaxf(v0.w, v1.w));
    }
    for (; i < i1; i += 4) {
        int r = i + ro;
        if (r < i1) {
            float4 xv = *(const float4*)(x + (size_t)r * DD + c4);
            float w = es[r] * inv; float2 q = mr[r];
            float4 v;
            v.x = ((xv.x - q.x) * q.y * gv.x + bv.x) * w;
            v.y = ((xv.y - q.x) * q.y * gv.y + bv.y) * w;
            v.z = ((xv.z - q.x) * q.y * gv.z + bv.z) * w;
            v.w = ((xv.w - q.x) * q.y * gv.w + bv.w) * w;
            acc.x += v.x; acc.y += v.y; acc.z += v.z; acc.w += v.w;
            amx.x = fmaxf(amx.x, v.x); amx.y = fmaxf(amx.y, v.y);
            amx.z = fmaxf(amx.z, v.z); amx.w = fmaxf(amx.w, v.w);
        }
    }
    __shared__ float lad[4][DD];
    __shared__ float lmx[4][DD];
    *(float4*)&lad[ro][c4] = acc;
    *(float4*)&lmx[ro][c4] = amx;
    __syncthreads();
    float a = lad[0][tid] + lad[1][tid] + lad[2][tid] + lad[3][tid];
    float m = fmaxf(fmaxf(lmx[0][tid], lmx[1][tid]), fmaxf(lmx[2][tid], lmx[3][tid]));
    size_t po = ((size_t)(t * BB + b) * SPLIT + part) * DD + tid;
    addp[po] = a;
    mxp[po]  = m;
}

// ---- Kernel F: pooling-partial reduce + final matmul (pool_reduce fused in) ----
__global__ __launch_bounds__(512) void mlp_kernel(
    const float* __restrict__ addp, const float* __restrict__ mxp,
    const float* __restrict__ Wm_i, const float* __restrict__ bm_i,
    const float* __restrict__ Wm_n, const float* __restrict__ bm_n,
    float* __restrict__ out)
{
    __shared__ float cat[2 * DD];
    __shared__ float psum[8][DD];
    int t = blockIdx.x >> 6;
    int b = blockIdx.x & 63;
    int tid = threadIdx.x;
    size_t pb = (size_t)blockIdx.x * SPLIT * DD + tid;
    float a = 0.0f, m = -FLT_MAX;
    #pragma unroll
    for (int p = 0; p < SPLIT; ++p) {
        a += addp[pb + (size_t)p * DD];
        m = fmaxf(m, mxp[pb + (size_t)p * DD]);
    }
    cat[tid]      = a;
    cat[DD + tid] = m;
    __syncthreads();
    const float* W = t ? Wm_n : Wm_i;
    int w = tid >> 6, lane = tid & 63;
    float acc[8] = {0, 0, 0, 0, 0, 0, 0, 0};
    int k0 = w * 128;
    for (int k = k0; k < k0 + 128; ++k) {
        float c = cat[k];                       // LDS broadcast
        #pragma unroll
        for (int j = 0; j < 8; ++j)
            acc[j] = fmaf(c, W[(size_t)k * DD + lane + 64 * j], acc[j]);
    }
    #pragma unroll
    for (int j = 0; j < 8; ++j) psum[w][lane + 64 * j] = acc[j];
    __syncthreads();
    float r = (t ? bm_n : bm_i)[tid];
    #pragma unroll
    for (int wv = 0; wv < 8; ++wv) r += psum[wv][tid];
    out[(size_t)b * (2 * DD) + t * DD + tid] = r;
}

extern "C" void kernel_launch(void* const* d_in, const int* in_sizes, int n_in,
                              void* d_out, int out_size, void* d_ws, size_t ws_size,
                              hipStream_t stream)
{
    const float* x_inst = (const float*)d_in[0];
    const float* x_net  = (const float*)d_in[1];
    const float* lng_i  = (const float*)d_in[2];
    const float* lnb_i  = (const float*)d_in[3];
    const float* lng_n  = (const float*)d_in[4];
    const float* lnb_n  = (const float*)d_in[5];
    const float* Wkqv_i = (const float*)d_in[6];
    const float* bkqv_i = (const float*)d_in[7];
    const float* Wkqv_n = (const float*)d_in[8];
    const float* bkqv_n = (const float*)d_in[9];
    const float* krw    = (const float*)d_in[10];
    const float* krb    = (const float*)d_in[11];
    const float* vrw    = (const float*)d_in[12];
    const float* vrb    = (const float*)d_in[13];
    const float* prel   = (const float*)d_in[14];
    const float* wout_i = (const float*)d_in[15];
    const float* bout_i = (const float*)d_in[16];
    const float* wout_n = (const float*)d_in[17];
    const float* bout_n = (const float*)d_in[18];
    const float* Wm_i   = (const float*)d_in[19];
    const float* bm_i   = (const float*)d_in[20];
    const float* Wm_n   = (const float*)d_in[21];
    const float* bm_n   = (const float*)d_in[22];
    const int* ei_i2n   = (const int*)d_in[23];
    const int* ei_n2i   = (const int*)d_in[24];
    const int* batch_i  = (const int*)d_in[25];
    const int* batch_n  = (const int*)d_in[26];

    float* base   = (float*)d_ws;
    float2* mr    = (float2*)base;             // 2N float2 (mean,rstd)
    float* ktvt   = base +  4 * (size_t)NN;    // 4N (interleaved kt,vt; inst then net)
    float* qp     = base +  8 * (size_t)NN;    // 2N
    float* esc    = base + 10 * (size_t)NN;    // 2N
    float* S      = base + 12 * (size_t)NN;    // 4N (2N float2)  <- zeroed
    float* bsum   = base + 16 * (size_t)NN;    // 256             <- zeroed
    float* addp   = bsum + 256;                // 2*BB*SPLIT*DD
    float* mxp    = addp + 2 * BB * SPLIT * DD;// 2*BB*SPLIT*DD
    float* gw     = mxp  + 2 * BB * SPLIT * DD;// 2*3*DD
    float* cAB    = gw + 2 * 3 * DD;           // 16

    (void)hipMemsetAsync(S, 0, 4 * (size_t)NN * sizeof(float), stream);
    (void)hipMemsetAsync(bsum, 0, 256 * sizeof(float), stream);

    prep_kernel<<<2, 512, 0, stream>>>(lng_i, lnb_i, lng_n, lnb_n,
        Wkqv_i, bkqv_i, Wkqv_n, bkqv_n, gw, cAB);

    ln_kqv_kernel<<<2 * NN / 8, 256, 0, stream>>>(x_inst, x_net, gw, cAB,
        krw, krb, vrw, vrb, prel, mr, (float2*)ktvt, qp);

    edge_attn_kernel<<<2048, 256, 0, stream>>>(ei_i2n, ei_n2i, ktvt, qp, S);

    score_bsum_kernel<<<2 * NN / 256, 256, 0, stream>>>((const float2*)S,
        wout_i, bout_i, wout_n, bout_n, batch_i, batch_n, esc, bsum);

    pool_kernel<<<2 * BB * SPLIT, 512, 0, stream>>>(x_inst, x_net,
        lng_i, lnb_i, lng_n, lnb_n, mr, esc, batch_i, batch_n,
        bsum, addp, mxp);

    mlp_kernel<<<2 * BB, 512, 0, stream>>>(addp, mxp, Wm_i, bm_i, Wm_n, bm_n,
        (float*)d_out);
}

// Round 11
// 457.934 us; speedup vs baseline: 1.3644x; 1.3644x over previous
//
#include <hip/hip_runtime.h>
#include <math.h>
#include <float.h>

#define NN 65536
#define EE 1048576
#define DD 512
#define BB 64
#define SPLIT 8
#define CAP 4608   // bucket capacity: Poisson(4096) + 8 sigma

// native (non-CAS) device-scope float atomic add (tiny bsum only)
__device__ __forceinline__ void fadd(float* p, float v) {
    unsafeAtomicAdd(p, v);
}

__device__ __forceinline__ int lowerb(const int* __restrict__ a, int n, int v) {
    int lo = 0, hi = n;
    while (lo < hi) { int mid = (lo + hi) >> 1; if (a[mid] < v) lo = mid + 1; else hi = mid; }
    return lo;
}

__device__ __forceinline__ float dot4(float4 a, float4 b) {
    return fmaf(a.x, b.x, fmaf(a.y, b.y, fmaf(a.z, b.z, a.w * b.w)));
}

// non-temporal float4 load: nt flag -> no-allocate / evict-first in caches.
// __builtin_nontemporal_load needs a NATIVE clang vector type (not
// HIP_vector_type), so go through ext_vector_type(4) float.
typedef float fx4 __attribute__((ext_vector_type(4)));
__device__ __forceinline__ float4 ntload4(const float4* p) {
    fx4 v = __builtin_nontemporal_load((const fx4*)p);
    return make_float4(v.x, v.y, v.z, v.w);
}

// ---- DPP wave reduce: sum lands in lane 63, pure VALU (no DS pipe) ----
template<int CTRL>
__device__ __forceinline__ float dppadd(float v) {
    union { float f; int i; } u, r;
    u.f = v;
    r.i = __builtin_amdgcn_update_dpp(0, u.i, CTRL, 0xF, 0xF, true);
    return v + r.f;
}
__device__ __forceinline__ float wave_sum63(float v) {
    v = dppadd<0x111>(v);   // row_shr:1
    v = dppadd<0x112>(v);   // row_shr:2
    v = dppadd<0x114>(v);   // row_shr:4
    v = dppadd<0x118>(v);   // row_shr:8  -> lane15 of each row16 holds row sum
    v = dppadd<0x142>(v);   // row_bcast:15
    v = dppadd<0x143>(v);   // row_bcast:31 -> lane63 holds wave sum
    return v;
}

// ---- Kernel P: precompute g*W columns + reduction scalars (input-only) ----
// gw : [2][3][DD]   g[d]*W[d][c]
// cAB: [2][8]       c0..2 = sum(g*Wc), c3..5 = sum(b*Wc)+bk[c]
__global__ __launch_bounds__(512) void prep_kernel(
    const float* __restrict__ g_i, const float* __restrict__ b_i,
    const float* __restrict__ g_n, const float* __restrict__ b_n,
    const float* __restrict__ W_i, const float* __restrict__ bk_i,
    const float* __restrict__ W_n, const float* __restrict__ bk_n,
    float* __restrict__ gw, float* __restrict__ cAB)
{
    int t = blockIdx.x;
    const float* g  = t ? g_n : g_i;
    const float* b  = t ? b_n : b_i;
    const float* W  = t ? W_n : W_i;
    const float* bk = t ? bk_n : bk_i;
    int d = threadIdx.x;
    float gv = g[d], bv = b[d];
    float w0 = W[d * 3 + 0], w1 = W[d * 3 + 1], w2 = W[d * 3 + 2];
    float v0 = gv * w0, v1 = gv * w1, v2 = gv * w2;
    gw[((size_t)t * 3 + 0) * DD + d] = v0;
    gw[((size_t)t * 3 + 1) * DD + d] = v1;
    gw[((size_t)t * 3 + 2) * DD + d] = v2;
    __shared__ float red[8];
    float vals[6] = { v0, v1, v2, bv * w0, bv * w1, bv * w2 };
    #pragma unroll
    for (int c = 0; c < 6; ++c) {
        float v = vals[c];
        #pragma unroll
        for (int o = 32; o; o >>= 1) v += __shfl_xor(v, o);
        if ((d & 63) == 0) red[d >> 6] = v;
        __syncthreads();
        if (d == 0) {
            float sum = 0.0f;
            #pragma unroll
            for (int w = 0; w < 8; ++w) sum += red[w];
            cAB[t * 8 + c] = sum + (c >= 3 ? bk[c - 3] : 0.0f);
        }
        __syncthreads();
    }
}

// ---- Kernel A: fused LayerNorm stats + kqv projection (round-4 best variant,
//      x loads non-temporal) ----
__global__ __launch_bounds__(256) void ln_kqv_kernel(
    const float* __restrict__ x_i, const float* __restrict__ x_n,
    const float* __restrict__ gw, const float* __restrict__ cAB,
    const float* __restrict__ krw, const float* __restrict__ krb,
    const float* __restrict__ vrw, const float* __restrict__ vrb,
    const float* __restrict__ prel,
    float2* __restrict__ mr_o, float2* __restrict__ ktvt2, float* __restrict__ qp)
{
    // grid = 2*NN/8 = 16384 blocks; 8192 per type; 2 rows per wave
    const int t  = blockIdx.x >> 13;
    const int nb = blockIdx.x & 8191;
    const float* x = t ? x_n : x_i;
    const int lane = threadIdx.x & 63;
    const int w    = threadIdx.x >> 6;
    const int row0 = nb * 8 + w * 2;

    const float4* xr0 = (const float4*)(x + (size_t)row0 * DD);
    const float4* xr1 = (const float4*)(x + (size_t)(row0 + 1) * DD);
    float4 xa0 = ntload4(xr0 + lane), xb0 = ntload4(xr0 + lane + 64);
    float4 xa1 = ntload4(xr1 + lane), xb1 = ntload4(xr1 + lane + 64);

    const float4* g0 = (const float4*)(gw + ((size_t)t * 3 + 0) * DD);
    const float4* g1 = (const float4*)(gw + ((size_t)t * 3 + 1) * DD);
    const float4* g2 = (const float4*)(gw + ((size_t)t * 3 + 2) * DD);
    float4 w0a = g0[lane], w0b = g0[lane + 64];
    float4 w1a = g1[lane], w1b = g1[lane + 64];
    float4 w2a = g2[lane], w2b = g2[lane + 64];

    const float* c = cAB + t * 8;
    float c0 = c[0], c1 = c[1], c2 = c[2], c3 = c[3], c4 = c[4], c5 = c[5];
    const int relk = t, relq = 1 - t;
    float ksc = krw[relk], kbi = krb[relk];
    float vsc = vrw[relk], vbi = vrb[relk];
    float psc = prel[relq];

    float s0  = xa0.x + xa0.y + xa0.z + xa0.w + xb0.x + xb0.y + xb0.z + xb0.w;
    float ss0 = dot4(xa0, xa0) + dot4(xb0, xb0);
    float p00 = dot4(xa0, w0a) + dot4(xb0, w0b);
    float p01 = dot4(xa0, w1a) + dot4(xb0, w1b);
    float p02 = dot4(xa0, w2a) + dot4(xb0, w2b);
    float s1  = xa1.x + xa1.y + xa1.z + xa1.w + xb1.x + xb1.y + xb1.z + xb1.w;
    float ss1 = dot4(xa1, xa1) + dot4(xb1, xb1);
    float p10 = dot4(xa1, w0a) + dot4(xb1, w0b);
    float p11 = dot4(xa1, w1a) + dot4(xb1, w1b);
    float p12 = dot4(xa1, w2a) + dot4(xb1, w2b);

    s0  = wave_sum63(s0);   s1  = wave_sum63(s1);
    ss0 = wave_sum63(ss0);  ss1 = wave_sum63(ss1);
    p00 = wave_sum63(p00);  p10 = wave_sum63(p10);
    p01 = wave_sum63(p01);  p11 = wave_sum63(p11);
    p02 = wave_sum63(p02);  p12 = wave_sum63(p12);

    if (lane == 63) {
        {
            float mean = s0 * (1.0f / DD);
            float var  = ss0 * (1.0f / DD) - mean * mean;
            float rstd = rsqrtf(var + 1e-5f);
            float kv = rstd * (p00 - mean * c0) + c3;
            float qv = rstd * (p01 - mean * c1) + c4;
            float vv = rstd * (p02 - mean * c2) + c5;
            int gn = t * NN + row0;
            mr_o[gn]  = make_float2(mean, rstd);
            ktvt2[gn] = make_float2(kv * ksc + kbi, vv * vsc + vbi);
            qp[gn]    = qv * psc;
        }
        {
            float mean = s1 * (1.0f / DD);
            float var  = ss1 * (1.0f / DD) - mean * mean;
            float rstd = rsqrtf(var + 1e-5f);
            float kv = rstd * (p10 - mean * c0) + c3;
            float qv = rstd * (p11 - mean * c1) + c4;
            float vv = rstd * (p12 - mean * c2) + c5;
            int gn = t * NN + row0 + 1;
            mr_o[gn]  = make_float2(mean, rstd);
            ktvt2[gn] = make_float2(kv * ksc + kbi, vv * vsc + vbi);
            qp[gn]    = qv * psc;
        }
    }
}

// ---- Kernel B1: edge scatter into coarse dst-buckets (plain stores; ~131K atomics total) ----
// blockIdx >> 8: 0 = i2n edges (dst=net, region 1), 1 = n2i edges (dst=inst, region 0)
__global__ __launch_bounds__(512) void edge_scatter_kernel(
    const int* __restrict__ ei_i2n, const int* __restrict__ ei_n2i,
    const float* __restrict__ ktvt, const float* __restrict__ qp,
    int* __restrict__ cursor, float2* __restrict__ pay, unsigned char* __restrict__ fb)
{
    __shared__ int hist[256];
    __shared__ int base[256];
    int es = blockIdx.x >> 8;
    int wg = blockIdx.x & 255;
    int tid = threadIdx.x;
    if (tid < 256) hist[tid] = 0;
    __syncthreads();
    const int* ei = es ? ei_n2i : ei_i2n;
    int soff = es ? NN : 0;      // src type base in ktvt
    int qoff = es ? 0 : NN;      // dst type base in qp
    int r    = es ? 0 : 1;       // dst region
    float e_[8], ev_[8]; int br_[8];
    int ebase = wg * 4096;
    #pragma unroll
    for (int j = 0; j < 8; ++j) {
        int idx = ebase + j * 512 + tid;
        int src = ei[idx], dst = ei[EE + idx];
        float2 kv = ((const float2*)ktvt)[soff + src];
        float e = __expf(qp[qoff + dst] * kv.x);
        e_[j] = e; ev_[j] = e * kv.y;
        int bin = dst >> 8;
        int rank = atomicAdd(&hist[bin], 1);           // LDS atomic, returns local rank
        br_[j] = (bin << 21) | ((dst & 255) << 13) | rank;
    }
    __syncthreads();
    if (tid < 256) {
        int c = hist[tid];
        base[tid] = c ? atomicAdd(&cursor[r * 256 + tid], c) : 0;
    }
    __syncthreads();
    #pragma unroll
    for (int j = 0; j < 8; ++j) {
        int br = br_[j];
        int bin = br >> 21, f = (br >> 13) & 255, rank = br & 8191;
        int slot = base[bin] + rank;
        if (slot < CAP) {
            size_t a = (size_t)(r * 256 + bin) * CAP + slot;
            float2 p; p.x = e_[j]; p.y = ev_[j];
            pay[a] = p;
            fb[a] = (unsigned char)f;
        }
    }
}

// ---- Kernel B2: per-bucket reduce -> S (plain stores, no global atomics, no S zeroing) ----
__global__ __launch_bounds__(256) void bucket_reduce_kernel(
    const int* __restrict__ cursor, const float2* __restrict__ pay,
    const unsigned char* __restrict__ fb, float2* __restrict__ S)
{
    __shared__ float b0[256], b1[256];
    int r = blockIdx.x >> 8, c = blockIdx.x & 255;
    int tid = threadIdx.x;
    b0[tid] = 0.0f; b1[tid] = 0.0f;
    __syncthreads();
    int cnt = min(cursor[r * 256 + c], CAP);
    size_t bb = (size_t)(r * 256 + c) * CAP;
    for (int i = tid; i < cnt; i += 256) {
        float2 p = pay[bb + i];
        int f = fb[bb + i];
        atomicAdd(&b0[f], p.x);        // LDS float atomic (ds_add_f32)
        atomicAdd(&b1[f], p.y);
    }
    __syncthreads();
    float2 o; o.x = b0[tid]; o.y = b1[tid];
    S[r * NN + c * 256 + tid] = o;
}

// ---- Kernel C: node score (exact GELU) + per-batch exp-sum ----
__global__ __launch_bounds__(256) void score_bsum_kernel(
    const float2* __restrict__ S,
    const float* __restrict__ wout_i, const float* __restrict__ bout_i,
    const float* __restrict__ wout_n, const float* __restrict__ bout_n,
    const int* __restrict__ batch_i, const int* __restrict__ batch_n,
    float* __restrict__ esc, float* __restrict__ bsum)
{
    __shared__ float lsum[BB];
    int tid = threadIdx.x;
    if (tid < BB) lsum[tid] = 0.0f;
    __syncthreads();
    int idx = blockIdx.x * 256 + tid;
    int t = idx >> 16;          // N = 2^16
    int n = idx & (NN - 1);
    float2 sv = S[idx];
    float aggr = (sv.x > 0.0f) ? sv.y / sv.x : 0.0f;
    float w  = t ? wout_n[0] : wout_i[0];
    float b0 = t ? bout_n[0] : bout_i[0];
    float z  = fmaf(aggr, w, b0);
    float sc = 0.5f * z * (1.0f + erff(z * 0.70710678118654752440f));
    float e  = __expf(sc);
    esc[idx] = e;
    int bb = t ? batch_n[n] : batch_i[n];
    atomicAdd(&lsum[bb], e);          // LDS atomic: native
    __syncthreads();
    if (tid < BB && lsum[tid] != 0.0f) fadd(&bsum[t * BB + tid], lsum[tid]);
}

// ---- Kernel D: pooling — float4 NT loads, 4 row-phases per block, LDS fold ----
__global__ __launch_bounds__(512) void pool_kernel(
    const float* __restrict__ x_i, const float* __restrict__ x_n,
    const float* __restrict__ g_i, const float* __restrict__ gbi,
    const float* __restrict__ g_n, const float* __restrict__ gbn,
    const float2* __restrict__ mr_, const float* __restrict__ esc,
    const int* __restrict__ batch_i, const int* __restrict__ batch_n,
    const float* __restrict__ bsum,
    float* __restrict__ addp, float* __restrict__ mxp)
{
    int gi = blockIdx.x;
    int t    = gi >> 9;                 // BB*SPLIT = 512 blocks per type
    int bi   = gi & 511;
    int b    = bi >> 3;                 // SPLIT = 8
    int part = bi & (SPLIT - 1);
    const float* x     = t ? x_n : x_i;
    const float* gwp   = t ? g_n : g_i;
    const float* gbp   = t ? gbn : gbi;
    const int*   batch = t ? batch_n : batch_i;
    const float2* mr   = mr_ + (size_t)t * NN;
    const float* es    = esc + (size_t)t * NN;
    int start = lowerb(batch, NN, b);
    int end   = lowerb(batch, NN, b + 1);
    int len   = end - start;
    int chunk = (len + SPLIT - 1) / SPLIT;
    int i0 = start + part * chunk;
    int i1 = min(i0 + chunk, end);
    if (i0 > i1) i1 = i0;
    int tid = threadIdx.x;
    int ro  = tid >> 7;                 // row offset 0..3
    int c4  = (tid & 127) << 2;         // column base 0..508
    float4 gv = *(const float4*)(gwp + c4);
    float4 bv = *(const float4*)(gbp + c4);
    float inv = 1.0f / bsum[t * BB + b];
    float4 acc = make_float4(0.0f, 0.0f, 0.0f, 0.0f);
    float4 amx = make_float4(-FLT_MAX, -FLT_MAX, -FLT_MAX, -FLT_MAX);
    int i = i0;
    for (; i + 8 <= i1; i += 8) {
        int r0 = i + ro, r1 = i + 4 + ro;
        float4 xv0 = ntload4((const float4*)(x + (size_t)r0 * DD + c4));
        float4 xv1 = ntload4((const float4*)(x + (size_t)r1 * DD + c4));
        float w0 = es[r0] * inv; float2 q0 = mr[r0];
        float w1 = es[r1] * inv; float2 q1 = mr[r1];
        float4 v0, v1;
        v0.x = ((xv0.x - q0.x) * q0.y * gv.x + bv.x) * w0;
        v0.y = ((xv0.y - q0.x) * q0.y * gv.y + bv.y) * w0;
        v0.z = ((xv0.z - q0.x) * q0.y * gv.z + bv.z) * w0;
        v0.w = ((xv0.w - q0.x) * q0.y * gv.w + bv.w) * w0;
        v1.x = ((xv1.x - q1.x) * q1.y * gv.x + bv.x) * w1;
        v1.y = ((xv1.y - q1.x) * q1.y * gv.y + bv.y) * w1;
        v1.z = ((xv1.z - q1.x) * q1.y * gv.z + bv.z) * w1;
        v1.w = ((xv1.w - q1.x) * q1.y * gv.w + bv.w) * w1;
        acc.x += v0.x + v1.x; acc.y += v0.y + v1.y;
        acc.z += v0.z + v1.z; acc.w += v0.w + v1.w;
        amx.x = fmaxf(amx.x, fmaxf(v0.x, v1.x));
        amx.y = fmaxf(amx.y, fmaxf(v0.y, v1.y));
        amx.z = fmaxf(amx.z, fmaxf(v0.z, v1.z));
        amx.w = fmaxf(amx.w, fmaxf(v0.w, v1.w));
    }
    for (; i < i1; i += 4) {
        int r = i + ro;
        if (r < i1) {
            float4 xv = ntload4((const float4*)(x + (size_t)r * DD + c4));
            float w = es[r] * inv; float2 q = mr[r];
            float4 v;
            v.x = ((xv.x - q.x) * q.y * gv.x + bv.x) * w;
            v.y = ((xv.y - q.x) * q.y * gv.y + bv.y) * w;
            v.z = ((xv.z - q.x) * q.y * gv.z + bv.z) * w;
            v.w = ((xv.w - q.x) * q.y * gv.w + bv.w) * w;
            acc.x += v.x; acc.y += v.y; acc.z += v.z; acc.w += v.w;
            amx.x = fmaxf(amx.x, v.x); amx.y = fmaxf(amx.y, v.y);
            amx.z = fmaxf(amx.z, v.z); amx.w = fmaxf(amx.w, v.w);
        }
    }
    __shared__ float lad[4][DD];
    __shared__ float lmx[4][DD];
    *(float4*)&lad[ro][c4] = acc;
    *(float4*)&lmx[ro][c4] = amx;
    __syncthreads();
    float a = lad[0][tid] + lad[1][tid] + lad[2][tid] + lad[3][tid];
    float m = fmaxf(fmaxf(lmx[0][tid], lmx[1][tid]), fmaxf(lmx[2][tid], lmx[3][tid]));
    size_t po = ((size_t)(t * BB + b) * SPLIT + part) * DD + tid;
    addp[po] = a;
    mxp[po]  = m;
}

// ---- Kernel F: pooling-partial reduce + final matmul (pool_reduce fused in) ----
__global__ __launch_bounds__(512) void mlp_kernel(
    const float* __restrict__ addp, const float* __restrict__ mxp,
    const float* __restrict__ Wm_i, const float* __restrict__ bm_i,
    const float* __restrict__ Wm_n, const float* __restrict__ bm_n,
    float* __restrict__ out)
{
    __shared__ float cat[2 * DD];
    __shared__ float psum[8][DD];
    int t = blockIdx.x >> 6;
    int b = blockIdx.x & 63;
    int tid = threadIdx.x;
    size_t pb = (size_t)blockIdx.x * SPLIT * DD + tid;
    float a = 0.0f, m = -FLT_MAX;
    #pragma unroll
    for (int p = 0; p < SPLIT; ++p) {
        a += addp[pb + (size_t)p * DD];
        m = fmaxf(m, mxp[pb + (size_t)p * DD]);
    }
    cat[tid]      = a;
    cat[DD + tid] = m;
    __syncthreads();
    const float* W = t ? Wm_n : Wm_i;
    int w = tid >> 6, lane = tid & 63;
    float acc[8] = {0, 0, 0, 0, 0, 0, 0, 0};
    int k0 = w * 128;
    for (int k = k0; k < k0 + 128; ++k) {
        float c = cat[k];                       // LDS broadcast
        #pragma unroll
        for (int j = 0; j < 8; ++j)
            acc[j] = fmaf(c, W[(size_t)k * DD + lane + 64 * j], acc[j]);
    }
    #pragma unroll
    for (int j = 0; j < 8; ++j) psum[w][lane + 64 * j] = acc[j];
    __syncthreads();
    float r = (t ? bm_n : bm_i)[tid];
    #pragma unroll
    for (int wv = 0; wv < 8; ++wv) r += psum[wv][tid];
    out[(size_t)b * (2 * DD) + t * DD + tid] = r;
}

extern "C" void kernel_launch(void* const* d_in, const int* in_sizes, int n_in,
                              void* d_out, int out_size, void* d_ws, size_t ws_size,
                              hipStream_t stream)
{
    const float* x_inst = (const float*)d_in[0];
    const float* x_net  = (const float*)d_in[1];
    const float* lng_i  = (const float*)d_in[2];
    const float* lnb_i  = (const float*)d_in[3];
    const float* lng_n  = (const float*)d_in[4];
    const float* lnb_n  = (const float*)d_in[5];
    const float* Wkqv_i = (const float*)d_in[6];
    const float* bkqv_i = (const float*)d_in[7];
    const float* Wkqv_n = (const float*)d_in[8];
    const float* bkqv_n = (const float*)d_in[9];
    const float* krw    = (const float*)d_in[10];
    const float* krb    = (const float*)d_in[11];
    const float* vrw    = (const float*)d_in[12];
    const float* vrb    = (const float*)d_in[13];
    const float* prel   = (const float*)d_in[14];
    const float* wout_i = (const float*)d_in[15];
    const float* bout_i = (const float*)d_in[16];
    const float* wout_n = (const float*)d_in[17];
    const float* bout_n = (const float*)d_in[18];
    const float* Wm_i   = (const float*)d_in[19];
    const float* bm_i   = (const float*)d_in[20];
    const float* Wm_n   = (const float*)d_in[21];
    const float* bm_n   = (const float*)d_in[22];
    const int* ei_i2n   = (const int*)d_in[23];
    const int* ei_n2i   = (const int*)d_in[24];
    const int* batch_i  = (const int*)d_in[25];
    const int* batch_n  = (const int*)d_in[26];

    float* base   = (float*)d_ws;
    float2* mr    = (float2*)base;             // 2N float2 (mean,rstd)
    float* ktvt   = base +  4 * (size_t)NN;    // 4N (interleaved kt,vt; inst then net)
    float* qp     = base +  8 * (size_t)NN;    // 2N
    float* esc    = base + 10 * (size_t)NN;    // 2N
    float2* S     = (float2*)(base + 12 * (size_t)NN);   // 2N float2
    int*   cursor = (int*)(base + 16 * (size_t)NN);      // 512 ints   <- zeroed
    float* bsum   = base + 16 * (size_t)NN + 512;        // 256        <- zeroed
    float* addp   = bsum + 256;                          // 2*BB*SPLIT*DD
    float* mxp    = addp + 2 * BB * SPLIT * DD;          // 2*BB*SPLIT*DD
    float2* pay   = (float2*)(mxp + 2 * BB * SPLIT * DD);        // 2*256*CAP float2
    unsigned char* fbb = (unsigned char*)(pay + 2 * 256 * (size_t)CAP); // 2*256*CAP bytes
    float* gw     = (float*)(fbb + 2 * 256 * (size_t)CAP);  // 2*3*DD
    float* cAB    = gw + 2 * 3 * DD;                        // 16

    (void)hipMemsetAsync(cursor, 0, (512 + 256) * sizeof(int), stream);

    prep_kernel<<<2, 512, 0, stream>>>(lng_i, lnb_i, lng_n, lnb_n,
        Wkqv_i, bkqv_i, Wkqv_n, bkqv_n, gw, cAB);

    ln_kqv_kernel<<<2 * NN / 8, 256, 0, stream>>>(x_inst, x_net, gw, cAB,
        krw, krb, vrw, vrb, prel, mr, (float2*)ktvt, qp);

    edge_scatter_kernel<<<512, 512, 0, stream>>>(ei_i2n, ei_n2i, ktvt, qp,
        cursor, pay, fbb);

    bucket_reduce_kernel<<<512, 256, 0, stream>>>(cursor, pay, fbb, S);

    score_bsum_kernel<<<2 * NN / 256, 256, 0, stream>>>(S,
        wout_i, bout_i, wout_n, bout_n, batch_i, batch_n, esc, bsum);

    pool_kernel<<<2 * BB * SPLIT, 512, 0, stream>>>(x_inst, x_net,
        lng_i, lnb_i, lng_n, lnb_n, mr, esc, batch_i, batch_n,
        bsum, addp, mxp);

    mlp_kernel<<<2 * BB, 512, 0, stream>>>(addp, mxp, Wm_i, bm_i, Wm_n, bm_n,
        (float*)d_out);
}